// Round 9
// baseline (123.098 us; speedup 1.0000x reference)
//
#include <hip/hip_runtime.h>

typedef _Float16 half8_t __attribute__((ext_vector_type(8)));
typedef _Float16 half4_t __attribute__((ext_vector_type(4)));
typedef float    float4_t __attribute__((ext_vector_type(4)));

// ---------------- ws layout (f16 elements unless noted) ----------------
// [0, 18432)        qkF   frag-order q,k weights:
//                   qkF[((f*3+kt)*64+lane)*8+j] = W_qkv[(kt*32+(lane>>4)*8+j)*288 + f*16+(lane&15)], f in [0,12)
// [18432, 27648)    vB    frag-order v-weights:
//                   vB[((f6*3+kt)*64+lane)*8+j] = W_qkv[(kt*32+(lane>>4)*8+j)*288 + 192+f6*16+(lane&15)]
// [27648, 36864)    woutB frag-order Wout (kt-pairs):
//                   woutB[((mt*3+kp)*64+lane)*8+s] = W_out[((2*kp+(s>>2))*16+(lane>>4)*4+(s&3))*96 + mt*16+(lane&15)]
// [36864 f16 = 73728 B, 77824 B)  biasT f32 [4][16][16]: biasT[m][j][i] = bias_m[i][j]
#define VB_OFF 18432
#define WOUTB_OFF 27648
#define BIAST_OFF_B 73728

__global__ void prep_kernel(const float* __restrict__ Wqkv,
                            const float* __restrict__ Wout,
                            const float* __restrict__ pos,
                            _Float16* __restrict__ wsh,
                            float* __restrict__ biasT) {
  int idx = blockIdx.x * 256 + threadIdx.x;
  if (idx < 18432) {
    int j = idx & 7, lane = (idx >> 3) & 63, fk = idx >> 9;   // fk in [0,36)
    int f = fk / 3, kt = fk % 3;
    int l15 = lane & 15, g = lane >> 4;
    int k = kt * 32 + g * 8 + j;                // input feature
    int fo = f * 16 + l15;                      // q,k output feature row
    wsh[idx] = (_Float16)Wqkv[k * 288 + fo];
  } else if (idx < 27648) {
    int t = idx - VB_OFF;
    int j = t & 7, lane = (t >> 3) & 63, fk = t >> 9;         // fk in [0,18)
    int f6 = fk / 3, kt = fk % 3;
    int l15 = lane & 15, g = lane >> 4;
    int k = kt * 32 + g * 8 + j;
    int fo = 192 + f6 * 16 + l15;               // v output feature row
    wsh[idx] = (_Float16)Wqkv[k * 288 + fo];
  } else if (idx < 36864) {
    int t = idx - WOUTB_OFF;
    int s = t & 7, lane = (t >> 3) & 63, fk = t >> 9;         // fk in [0,18)
    int mt = fk / 3, kp = fk % 3;
    int l15 = lane & 15, g = lane >> 4;
    int kt = kp * 2 + (s >> 2), j = s & 3;
    int k = kt * 16 + g * 4 + j;                // attn feature
    int fo = mt * 16 + l15;                     // out feature
    wsh[idx] = (_Float16)Wout[k * 96 + fo];
  } else if (idx < 36864 + 1024) {
    int t = idx - 36864;
    int m = t >> 8, j = (t >> 4) & 15, i = t & 15;            // store [j][i] = bias[i][j]
    int xi = i >> 2, yi = i & 3, xj = j >> 2, yj = j & 3;
    float v = pos[(xj - xi + 3) * 7 + (yj - yi + 3)];         // key minus query
    if ((m & 1) && ((i >= 8) != (j >= 8))) v -= 1e9f;         // ul mask (last window row)
    if ((m & 2) && ((yi >= 2) != (yj >= 2))) v -= 1e9f;       // lr mask (last window col)
    biasT[t] = v;
  }
}

static __device__ __forceinline__ half4_t pack4(float4_t a) {
  half4_t h;
  h[0] = (_Float16)a[0]; h[1] = (_Float16)a[1];
  h[2] = (_Float16)a[2]; h[3] = (_Float16)a[3];
  return h;
}

static __device__ __forceinline__ void gload_lds16(const void* g, void* l) {
  __builtin_amdgcn_global_load_lds(
      (const __attribute__((address_space(1))) unsigned int*)g,
      (__attribute__((address_space(3))) unsigned int*)l, 16, 0, 0);
}

// 512-thread blocks (8 waves), 2 windows/wave, 16 windows/block. q,k weights
// frag-order in LDS (36864 B linear staging -> 4 blocks/CU possible); v/Wout
// frag-order from L1/L2; all intermediates register-chained; no-max softmax.
// launch_bounds(512,6): VGPR cap 85 >= observed demand ~64 -> no spill.
__global__ __launch_bounds__(512, 6)
void swin_fused(const float* __restrict__ x,
                const _Float16* __restrict__ wsh,
                const float* __restrict__ biasT,
                const float* __restrict__ b_out,
                float* __restrict__ out) {
  __shared__ _Float16 qkL[18432];   // 36864 B, frag-order
  const int tid  = threadIdx.x;
  const int wave = tid >> 6;
  const int lane = tid & 63;
  const int l15  = lane & 15;
  const int g    = lane >> 4;
  const int ty = l15 >> 2, tx = l15 & 3;

  const int blk   = blockIdx.x;
  const int batch = blk / 49;
  const int wbase = (blk % 49) * 16 + wave * 2;   // this wave's 2 windows

  // per-window token positions (cyclic shift folded in; reused for stores)
  int pp[2], qq[2];
#pragma unroll
  for (int w = 0; w < 2; ++w) {
    int wid = wbase + w;
    int wrow = wid / 28, wcol = wid % 28;
    int p = wrow * 4 + ty + 2; if (p >= 112) p -= 112;
    int q = wcol * 4 + tx + 2; if (q >= 112) q -= 112;
    pp[w] = p; qq[w] = q;
  }

  // ---- issue x loads
  float4_t xa[2][3], xb[2][3];
#pragma unroll
  for (int w = 0; w < 2; ++w) {
    const float* xr = x + (((size_t)batch * 112 + pp[w]) * 112 + qq[w]) * 96 + g * 8;
#pragma unroll
    for (int kt = 0; kt < 3; ++kt) {
      xa[w][kt] = *(const float4_t*)(xr + kt * 32);
      xb[w][kt] = *(const float4_t*)(xr + kt * 32 + 4);
    }
  }

  // ---- async stage qkF (linear copy: 2304 16B chunks over 8 waves)
  {
    const char* gs = (const char*)wsh;
    char* lb = (char*)qkL;
#pragma unroll
    for (int k = 0; k < 5; ++k) {
      int cb = k * 512 + wave * 64;          // wave-uniform chunk base
      if (cb < 2304) {
        size_t off = (size_t)(cb + lane) * 16;
        gload_lds16(gs + off, lb + off);
      }
    }
  }

  // ---- per-window bias values
  float bb0[2], bb1[2], bb2[2], bb3[2];
#pragma unroll
  for (int w = 0; w < 2; ++w) {
    int wid = wbase + w;
    int var = ((wid / 28) == 27 ? 1 : 0) + ((wid % 28) == 27 ? 2 : 0);
    const float* bt = biasT + var * 256 + g * 64 + l15;   // [var][j=4g+r][i=l15]
    bb0[w] = bt[0]; bb1[w] = bt[16]; bb2[w] = bt[32]; bb3[w] = bt[48];
  }

  // ---- convert x to f16 fragments
  half8_t xf[2][3];
#pragma unroll
  for (int w = 0; w < 2; ++w)
#pragma unroll
    for (int kt = 0; kt < 3; ++kt) {
      half8_t h;
      h[0] = (_Float16)xa[w][kt][0]; h[1] = (_Float16)xa[w][kt][1];
      h[2] = (_Float16)xa[w][kt][2]; h[3] = (_Float16)xa[w][kt][3];
      h[4] = (_Float16)xb[w][kt][0]; h[5] = (_Float16)xb[w][kt][1];
      h[6] = (_Float16)xb[w][kt][2]; h[7] = (_Float16)xb[w][kt][3];
      xf[w][kt] = h;
    }

  __syncthreads();   // staging complete (barrier drains vmcnt incl. global_load_lds)

  const _Float16* vB    = wsh + VB_OFF;
  const _Float16* woutB = wsh + WOUTB_OFF;
  const float scale = 0.17677669529663687f;  // 32^-0.5

  // ---- per-window compute, intermediates register-chained
#pragma unroll
  for (int w = 0; w < 2; ++w) {
    // GEMM1 q,k tiles: D = Wqk_slice @ x^T; A-frags = conflict-free lane-linear b128
    half4_t qk16[12];
#pragma unroll
    for (int f = 0; f < 12; ++f) {
      half8_t w0 = *(const half8_t*)&qkL[((f * 3 + 0) * 64 + lane) * 8];
      half8_t w1 = *(const half8_t*)&qkL[((f * 3 + 1) * 64 + lane) * 8];
      half8_t w2 = *(const half8_t*)&qkL[((f * 3 + 2) * 64 + lane) * 8];
      float4_t acc = {0.f, 0.f, 0.f, 0.f};
      acc = __builtin_amdgcn_mfma_f32_16x16x32_f16(w0, xf[w][0], acc, 0, 0, 0);
      acc = __builtin_amdgcn_mfma_f32_16x16x32_f16(w1, xf[w][1], acc, 0, 0, 0);
      acc = __builtin_amdgcn_mfma_f32_16x16x32_f16(w2, xf[w][2], acc, 0, 0, 0);
      qk16[f] = pack4(acc);
    }
    // GEMM1 v tiles: D = x @ Wv_slice; B-frags are coalesced b128 loads (L1)
    half4_t vt16[6];
#pragma unroll
    for (int f6 = 0; f6 < 6; ++f6) {
      float4_t acc = {0.f, 0.f, 0.f, 0.f};
#pragma unroll
      for (int kt = 0; kt < 3; ++kt) {
        half8_t vb = *(const half8_t*)&vB[((f6 * 3 + kt) * 64 + lane) * 8];
        acc = __builtin_amdgcn_mfma_f32_16x16x32_f16(xf[w][kt], vb, acc, 0, 0, 0);
      }
      vt16[f6] = pack4(acc);
    }

    // attention: QK^T + exp (no max-subtract; masked = -1e9 -> exp 0), batched shuffles
    float ps[3][4], ss[3];
#pragma unroll
    for (int h = 0; h < 3; ++h) {
      float4_t dd = {0.f, 0.f, 0.f, 0.f};
      dd = __builtin_amdgcn_mfma_f32_16x16x16f16(qk16[6 + 2 * h], qk16[2 * h],     dd, 0, 0, 0);
      dd = __builtin_amdgcn_mfma_f32_16x16x16f16(qk16[7 + 2 * h], qk16[2 * h + 1], dd, 0, 0, 0);
      ps[h][0] = __expf(fmaf(dd[0], scale, bb0[w]));
      ps[h][1] = __expf(fmaf(dd[1], scale, bb1[w]));
      ps[h][2] = __expf(fmaf(dd[2], scale, bb2[w]));
      ps[h][3] = __expf(fmaf(dd[3], scale, bb3[w]));
      ss[h] = (ps[h][0] + ps[h][1]) + (ps[h][2] + ps[h][3]);
    }
    ss[0] += __shfl_xor(ss[0], 16, 64);
    ss[1] += __shfl_xor(ss[1], 16, 64);
    ss[2] += __shfl_xor(ss[2], 16, 64);
    ss[0] += __shfl_xor(ss[0], 32, 64);
    ss[1] += __shfl_xor(ss[1], 32, 64);
    ss[2] += __shfl_xor(ss[2], 32, 64);

    half4_t ao[6];
#pragma unroll
    for (int h = 0; h < 3; ++h) {
      float r = __builtin_amdgcn_rcpf(ss[h]);
      half4_t pb;   // P^T: B operand (col=query l15, k=key 4g+r)
      pb[0] = (_Float16)(ps[h][0] * r); pb[1] = (_Float16)(ps[h][1] * r);
      pb[2] = (_Float16)(ps[h][2] * r); pb[3] = (_Float16)(ps[h][3] * r);
      float4_t o0 = {0.f, 0.f, 0.f, 0.f};
      o0 = __builtin_amdgcn_mfma_f32_16x16x16f16(vt16[2 * h], pb, o0, 0, 0, 0);
      ao[2 * h] = pack4(o0);
      float4_t o1 = {0.f, 0.f, 0.f, 0.f};
      o1 = __builtin_amdgcn_mfma_f32_16x16x16f16(vt16[2 * h + 1], pb, o1, 0, 0, 0);
      ao[2 * h + 1] = pack4(o1);
    }

    // GEMM3: y^T = Wout^T @ ao^T; A-frags as coalesced b128 kt-pair loads (L1)
    float* orow = out + (((size_t)batch * 112 + pp[w]) * 112 + qq[w]) * 96;
#pragma unroll
    for (int mt = 0; mt < 6; ++mt) {
      float4_t acc = {0.f, 0.f, 0.f, 0.f};
#pragma unroll
      for (int kp = 0; kp < 3; ++kp) {
        half8_t wp = *(const half8_t*)&woutB[((mt * 3 + kp) * 64 + lane) * 8];
        half4_t lo = __builtin_shufflevector(wp, wp, 0, 1, 2, 3);
        half4_t hi = __builtin_shufflevector(wp, wp, 4, 5, 6, 7);
        acc = __builtin_amdgcn_mfma_f32_16x16x16f16(lo, ao[2 * kp],     acc, 0, 0, 0);
        acc = __builtin_amdgcn_mfma_f32_16x16x16f16(hi, ao[2 * kp + 1], acc, 0, 0, 0);
      }
      float4_t bb = *(const float4_t*)&b_out[mt * 16 + g * 4];
      acc[0] += bb[0]; acc[1] += bb[1]; acc[2] += bb[2]; acc[3] += bb[3];
      *(float4_t*)&orow[mt * 16 + g * 4] = acc;
    }
  }
}

extern "C" void kernel_launch(void* const* d_in, const int* in_sizes, int n_in,
                              void* d_out, int out_size, void* d_ws, size_t ws_size,
                              hipStream_t stream) {
  const float* x    = (const float*)d_in[0];
  const float* Wqkv = (const float*)d_in[1];
  const float* pos  = (const float*)d_in[2];
  const float* Wout = (const float*)d_in[3];
  const float* bout = (const float*)d_in[4];
  char* ws = (char*)d_ws;
  _Float16* wsh  = (_Float16*)ws;
  float* biasT = (float*)(ws + BIAST_OFF_B);

  prep_kernel<<<148, 256, 0, stream>>>(Wqkv, Wout, pos, wsh, biasT);
  swin_fused<<<1568, 512, 0, stream>>>(x, wsh, biasT, bout, (float*)d_out);
}

// Round 10
// 112.570 us; speedup vs baseline: 1.0935x; 1.0935x over previous
//
#include <hip/hip_runtime.h>

typedef _Float16 half8_t __attribute__((ext_vector_type(8)));
typedef _Float16 half4_t __attribute__((ext_vector_type(4)));
typedef float    float4_t __attribute__((ext_vector_type(4)));

// ---------------- ws layout (f16 elements unless noted) ----------------
// [0, 18432)        qkF   frag-order q,k weights:
//                   qkF[((f*3+kt)*64+lane)*8+j] = W_qkv[(kt*32+(lane>>4)*8+j)*288 + f*16+(lane&15)], f in [0,12)
// [18432, 27648)    vB    frag-order v-weights:
//                   vB[((f6*3+kt)*64+lane)*8+j] = W_qkv[(kt*32+(lane>>4)*8+j)*288 + 192+f6*16+(lane&15)]
// [27648, 36864)    woutB frag-order Wout (kt-pairs):
//                   woutB[((mt*3+kp)*64+lane)*8+s] = W_out[((2*kp+(s>>2))*16+(lane>>4)*4+(s&3))*96 + mt*16+(lane&15)]
// [36864 f16 = 73728 B, 77824 B)  biasT f32 [4][16][16]: biasT[m][j][i] = bias_m[i][j]
#define VB_OFF 18432
#define WOUTB_OFF 27648
#define BIAST_OFF_B 73728

__global__ void prep_kernel(const float* __restrict__ Wqkv,
                            const float* __restrict__ Wout,
                            const float* __restrict__ pos,
                            _Float16* __restrict__ wsh,
                            float* __restrict__ biasT) {
  int idx = blockIdx.x * 256 + threadIdx.x;
  if (idx < 18432) {
    int j = idx & 7, lane = (idx >> 3) & 63, fk = idx >> 9;   // fk in [0,36)
    int f = fk / 3, kt = fk % 3;
    int l15 = lane & 15, g = lane >> 4;
    int k = kt * 32 + g * 8 + j;                // input feature
    int fo = f * 16 + l15;                      // q,k output feature row
    wsh[idx] = (_Float16)Wqkv[k * 288 + fo];
  } else if (idx < 27648) {
    int t = idx - VB_OFF;
    int j = t & 7, lane = (t >> 3) & 63, fk = t >> 9;         // fk in [0,18)
    int f6 = fk / 3, kt = fk % 3;
    int l15 = lane & 15, g = lane >> 4;
    int k = kt * 32 + g * 8 + j;
    int fo = 192 + f6 * 16 + l15;               // v output feature row
    wsh[idx] = (_Float16)Wqkv[k * 288 + fo];
  } else if (idx < 36864) {
    int t = idx - WOUTB_OFF;
    int s = t & 7, lane = (t >> 3) & 63, fk = t >> 9;         // fk in [0,18)
    int mt = fk / 3, kp = fk % 3;
    int l15 = lane & 15, g = lane >> 4;
    int kt = kp * 2 + (s >> 2), j = s & 3;
    int k = kt * 16 + g * 4 + j;                // attn feature
    int fo = mt * 16 + l15;                     // out feature
    wsh[idx] = (_Float16)Wout[k * 96 + fo];
  } else if (idx < 36864 + 1024) {
    int t = idx - 36864;
    int m = t >> 8, j = (t >> 4) & 15, i = t & 15;            // store [j][i] = bias[i][j]
    int xi = i >> 2, yi = i & 3, xj = j >> 2, yj = j & 3;
    float v = pos[(xj - xi + 3) * 7 + (yj - yi + 3)];         // key minus query
    if ((m & 1) && ((i >= 8) != (j >= 8))) v -= 1e9f;         // ul mask (last window row)
    if ((m & 2) && ((yi >= 2) != (yj >= 2))) v -= 1e9f;       // lr mask (last window col)
    biasT[t] = v;
  }
}

static __device__ __forceinline__ half4_t pack4(float4_t a) {
  half4_t h;
  h[0] = (_Float16)a[0]; h[1] = (_Float16)a[1];
  h[2] = (_Float16)a[2]; h[3] = (_Float16)a[3];
  return h;
}

static __device__ __forceinline__ void gload_lds16(const void* g, void* l) {
  __builtin_amdgcn_global_load_lds(
      (const __attribute__((address_space(1))) unsigned int*)g,
      (__attribute__((address_space(3))) unsigned int*)l, 16, 0, 0);
}

// 256-thread blocks (4 waves), 2 windows/wave. q,k weights frag-order in LDS
// (36864 B, linear async staging, conflict-free lane-linear reads); v/Wout
// frag-order from L1; intermediates register-chained; no-max softmax.
// launch_bounds(256,4): VGPR cap 128 >= demand (~64-96, r8-proven) -> no spill;
// 4 blocks/CU x 36.9 KB = 147.5 KB LDS -> 16 waves/CU.
__global__ __launch_bounds__(256, 4)
void swin_fused(const float* __restrict__ x,
                const _Float16* __restrict__ wsh,
                const float* __restrict__ biasT,
                const float* __restrict__ b_out,
                float* __restrict__ out) {
  __shared__ _Float16 qkL[18432];   // 36864 B, frag-order
  const int tid  = threadIdx.x;
  const int wave = tid >> 6;
  const int lane = tid & 63;
  const int l15  = lane & 15;
  const int g    = lane >> 4;
  const int ty = l15 >> 2, tx = l15 & 3;

  const int blk   = blockIdx.x;
  const int batch = blk / 98;
  const int wbase = (blk % 98) * 8 + wave * 2;   // this wave's 2 windows

  // per-window token positions (cyclic shift folded in; reused for stores)
  int pp[2], qq[2];
#pragma unroll
  for (int w = 0; w < 2; ++w) {
    int wid = wbase + w;
    int wrow = wid / 28, wcol = wid % 28;
    int p = wrow * 4 + ty + 2; if (p >= 112) p -= 112;
    int q = wcol * 4 + tx + 2; if (q >= 112) q -= 112;
    pp[w] = p; qq[w] = q;
  }

  // ---- issue x loads
  float4_t xa[2][3], xb[2][3];
#pragma unroll
  for (int w = 0; w < 2; ++w) {
    const float* xr = x + (((size_t)batch * 112 + pp[w]) * 112 + qq[w]) * 96 + g * 8;
#pragma unroll
    for (int kt = 0; kt < 3; ++kt) {
      xa[w][kt] = *(const float4_t*)(xr + kt * 32);
      xb[w][kt] = *(const float4_t*)(xr + kt * 32 + 4);
    }
  }

  // ---- async stage qkF (linear copy: 2304 16B chunks over 4 waves)
  {
    const char* gs = (const char*)wsh;
    char* lb = (char*)qkL;
#pragma unroll
    for (int k = 0; k < 9; ++k) {
      int cb = k * 256 + wave * 64;          // wave-uniform chunk base, max 2240 < 2304
      size_t off = (size_t)(cb + lane) * 16;
      gload_lds16(gs + off, lb + off);
    }
  }

  // ---- per-window bias values
  float bb0[2], bb1[2], bb2[2], bb3[2];
#pragma unroll
  for (int w = 0; w < 2; ++w) {
    int wid = wbase + w;
    int var = ((wid / 28) == 27 ? 1 : 0) + ((wid % 28) == 27 ? 2 : 0);
    const float* bt = biasT + var * 256 + g * 64 + l15;   // [var][j=4g+r][i=l15]
    bb0[w] = bt[0]; bb1[w] = bt[16]; bb2[w] = bt[32]; bb3[w] = bt[48];
  }

  // ---- convert x to f16 fragments
  half8_t xf[2][3];
#pragma unroll
  for (int w = 0; w < 2; ++w)
#pragma unroll
    for (int kt = 0; kt < 3; ++kt) {
      half8_t h;
      h[0] = (_Float16)xa[w][kt][0]; h[1] = (_Float16)xa[w][kt][1];
      h[2] = (_Float16)xa[w][kt][2]; h[3] = (_Float16)xa[w][kt][3];
      h[4] = (_Float16)xb[w][kt][0]; h[5] = (_Float16)xb[w][kt][1];
      h[6] = (_Float16)xb[w][kt][2]; h[7] = (_Float16)xb[w][kt][3];
      xf[w][kt] = h;
    }

  __syncthreads();   // staging complete (barrier drains vmcnt incl. global_load_lds)

  const _Float16* vB    = wsh + VB_OFF;
  const _Float16* woutB = wsh + WOUTB_OFF;
  const float scale = 0.17677669529663687f;  // 32^-0.5

  // ---- per-window compute, intermediates register-chained
#pragma unroll
  for (int w = 0; w < 2; ++w) {
    // GEMM1 q,k tiles: D = Wqk_slice @ x^T; A-frags = conflict-free lane-linear b128
    half4_t qk16[12];
#pragma unroll
    for (int f = 0; f < 12; ++f) {
      half8_t w0 = *(const half8_t*)&qkL[((f * 3 + 0) * 64 + lane) * 8];
      half8_t w1 = *(const half8_t*)&qkL[((f * 3 + 1) * 64 + lane) * 8];
      half8_t w2 = *(const half8_t*)&qkL[((f * 3 + 2) * 64 + lane) * 8];
      float4_t acc = {0.f, 0.f, 0.f, 0.f};
      acc = __builtin_amdgcn_mfma_f32_16x16x32_f16(w0, xf[w][0], acc, 0, 0, 0);
      acc = __builtin_amdgcn_mfma_f32_16x16x32_f16(w1, xf[w][1], acc, 0, 0, 0);
      acc = __builtin_amdgcn_mfma_f32_16x16x32_f16(w2, xf[w][2], acc, 0, 0, 0);
      qk16[f] = pack4(acc);
    }
    // GEMM1 v tiles: D = x @ Wv_slice; B-frags are coalesced b128 loads (L1)
    half4_t vt16[6];
#pragma unroll
    for (int f6 = 0; f6 < 6; ++f6) {
      float4_t acc = {0.f, 0.f, 0.f, 0.f};
#pragma unroll
      for (int kt = 0; kt < 3; ++kt) {
        half8_t vb = *(const half8_t*)&vB[((f6 * 3 + kt) * 64 + lane) * 8];
        acc = __builtin_amdgcn_mfma_f32_16x16x32_f16(xf[w][kt], vb, acc, 0, 0, 0);
      }
      vt16[f6] = pack4(acc);
    }

    // attention: QK^T + exp (no max-subtract; masked = -1e9 -> exp 0), batched shuffles
    float ps[3][4], ss[3];
#pragma unroll
    for (int h = 0; h < 3; ++h) {
      float4_t dd = {0.f, 0.f, 0.f, 0.f};
      dd = __builtin_amdgcn_mfma_f32_16x16x16f16(qk16[6 + 2 * h], qk16[2 * h],     dd, 0, 0, 0);
      dd = __builtin_amdgcn_mfma_f32_16x16x16f16(qk16[7 + 2 * h], qk16[2 * h + 1], dd, 0, 0, 0);
      ps[h][0] = __expf(fmaf(dd[0], scale, bb0[w]));
      ps[h][1] = __expf(fmaf(dd[1], scale, bb1[w]));
      ps[h][2] = __expf(fmaf(dd[2], scale, bb2[w]));
      ps[h][3] = __expf(fmaf(dd[3], scale, bb3[w]));
      ss[h] = (ps[h][0] + ps[h][1]) + (ps[h][2] + ps[h][3]);
    }
    ss[0] += __shfl_xor(ss[0], 16, 64);
    ss[1] += __shfl_xor(ss[1], 16, 64);
    ss[2] += __shfl_xor(ss[2], 16, 64);
    ss[0] += __shfl_xor(ss[0], 32, 64);
    ss[1] += __shfl_xor(ss[1], 32, 64);
    ss[2] += __shfl_xor(ss[2], 32, 64);

    half4_t ao[6];
#pragma unroll
    for (int h = 0; h < 3; ++h) {
      float r = __builtin_amdgcn_rcpf(ss[h]);
      half4_t pb;   // P^T: B operand (col=query l15, k=key 4g+r)
      pb[0] = (_Float16)(ps[h][0] * r); pb[1] = (_Float16)(ps[h][1] * r);
      pb[2] = (_Float16)(ps[h][2] * r); pb[3] = (_Float16)(ps[h][3] * r);
      float4_t o0 = {0.f, 0.f, 0.f, 0.f};
      o0 = __builtin_amdgcn_mfma_f32_16x16x16f16(vt16[2 * h], pb, o0, 0, 0, 0);
      ao[2 * h] = pack4(o0);
      float4_t o1 = {0.f, 0.f, 0.f, 0.f};
      o1 = __builtin_amdgcn_mfma_f32_16x16x16f16(vt16[2 * h + 1], pb, o1, 0, 0, 0);
      ao[2 * h + 1] = pack4(o1);
    }

    // GEMM3: y^T = Wout^T @ ao^T; A-frags as coalesced b128 kt-pair loads (L1)
    float* orow = out + (((size_t)batch * 112 + pp[w]) * 112 + qq[w]) * 96;
#pragma unroll
    for (int mt = 0; mt < 6; ++mt) {
      float4_t acc = {0.f, 0.f, 0.f, 0.f};
#pragma unroll
      for (int kp = 0; kp < 3; ++kp) {
        half8_t wp = *(const half8_t*)&woutB[((mt * 3 + kp) * 64 + lane) * 8];
        half4_t lo = __builtin_shufflevector(wp, wp, 0, 1, 2, 3);
        half4_t hi = __builtin_shufflevector(wp, wp, 4, 5, 6, 7);
        acc = __builtin_amdgcn_mfma_f32_16x16x16f16(lo, ao[2 * kp],     acc, 0, 0, 0);
        acc = __builtin_amdgcn_mfma_f32_16x16x16f16(hi, ao[2 * kp + 1], acc, 0, 0, 0);
      }
      float4_t bb = *(const float4_t*)&b_out[mt * 16 + g * 4];
      acc[0] += bb[0]; acc[1] += bb[1]; acc[2] += bb[2]; acc[3] += bb[3];
      *(float4_t*)&orow[mt * 16 + g * 4] = acc;
    }
  }
}

extern "C" void kernel_launch(void* const* d_in, const int* in_sizes, int n_in,
                              void* d_out, int out_size, void* d_ws, size_t ws_size,
                              hipStream_t stream) {
  const float* x    = (const float*)d_in[0];
  const float* Wqkv = (const float*)d_in[1];
  const float* pos  = (const float*)d_in[2];
  const float* Wout = (const float*)d_in[3];
  const float* bout = (const float*)d_in[4];
  char* ws = (char*)d_ws;
  _Float16* wsh  = (_Float16*)ws;
  float* biasT = (float*)(ws + BIAST_OFF_B);

  prep_kernel<<<148, 256, 0, stream>>>(Wqkv, Wout, pos, wsh, biasT);
  swin_fused<<<3136, 256, 0, stream>>>(x, wsh, biasT, bout, (float*)d_out);
}

// Round 11
// 96.227 us; speedup vs baseline: 1.2792x; 1.1698x over previous
//
#include <hip/hip_runtime.h>

typedef _Float16 half8_t __attribute__((ext_vector_type(8)));
typedef _Float16 half4_t __attribute__((ext_vector_type(4)));
typedef float    float4_t __attribute__((ext_vector_type(4)));

// ---------------- ws layout (f16 elements unless noted) ----------------
// [0, 18432)        qkF   frag-order q,k weights:
//                   qkF[((f*3+kt)*64+lane)*8+j] = W_qkv[(kt*32+(lane>>4)*8+j)*288 + f*16+(lane&15)], f in [0,12)
// [18432, 27648)    vB    frag-order v-weights:
//                   vB[((f6*3+kt)*64+lane)*8+j] = W_qkv[(kt*32+(lane>>4)*8+j)*288 + 192+f6*16+(lane&15)]
// [27648, 36864)    woutB frag-order Wout (kt-pairs):
//                   woutB[((mt*3+kp)*64+lane)*8+s] = W_out[((2*kp+(s>>2))*16+(lane>>4)*4+(s&3))*96 + mt*16+(lane&15)]
// [36864 f16 = 73728 B, 77824 B)  biasT f32 [4][16][16]: biasT[m][j][i] = bias_m[i][j]
#define VB_OFF 18432
#define WOUTB_OFF 27648
#define BIAST_OFF_B 73728

__global__ void prep_kernel(const float* __restrict__ Wqkv,
                            const float* __restrict__ Wout,
                            const float* __restrict__ pos,
                            _Float16* __restrict__ wsh,
                            float* __restrict__ biasT) {
  int idx = blockIdx.x * 256 + threadIdx.x;
  if (idx < 18432) {
    int j = idx & 7, lane = (idx >> 3) & 63, fk = idx >> 9;   // fk in [0,36)
    int f = fk / 3, kt = fk % 3;
    int l15 = lane & 15, g = lane >> 4;
    int k = kt * 32 + g * 8 + j;                // input feature
    int fo = f * 16 + l15;                      // q,k output feature row
    wsh[idx] = (_Float16)Wqkv[k * 288 + fo];
  } else if (idx < 27648) {
    int t = idx - VB_OFF;
    int j = t & 7, lane = (t >> 3) & 63, fk = t >> 9;         // fk in [0,18)
    int f6 = fk / 3, kt = fk % 3;
    int l15 = lane & 15, g = lane >> 4;
    int k = kt * 32 + g * 8 + j;
    int fo = 192 + f6 * 16 + l15;               // v output feature row
    wsh[idx] = (_Float16)Wqkv[k * 288 + fo];
  } else if (idx < 36864) {
    int t = idx - WOUTB_OFF;
    int s = t & 7, lane = (t >> 3) & 63, fk = t >> 9;         // fk in [0,18)
    int mt = fk / 3, kp = fk % 3;
    int l15 = lane & 15, g = lane >> 4;
    int kt = kp * 2 + (s >> 2), j = s & 3;
    int k = kt * 16 + g * 4 + j;                // attn feature
    int fo = mt * 16 + l15;                     // out feature
    wsh[idx] = (_Float16)Wout[k * 96 + fo];
  } else if (idx < 36864 + 1024) {
    int t = idx - 36864;
    int m = t >> 8, j = (t >> 4) & 15, i = t & 15;            // store [j][i] = bias[i][j]
    int xi = i >> 2, yi = i & 3, xj = j >> 2, yj = j & 3;
    float v = pos[(xj - xi + 3) * 7 + (yj - yi + 3)];         // key minus query
    if ((m & 1) && ((i >= 8) != (j >= 8))) v -= 1e9f;         // ul mask (last window row)
    if ((m & 2) && ((yi >= 2) != (yj >= 2))) v -= 1e9f;       // lr mask (last window col)
    biasT[t] = v;
  }
}

static __device__ __forceinline__ half4_t pack4(float4_t a) {
  half4_t h;
  h[0] = (_Float16)a[0]; h[1] = (_Float16)a[1];
  h[2] = (_Float16)a[2]; h[3] = (_Float16)a[3];
  return h;
}

static __device__ __forceinline__ void gload_lds16(const void* g, void* l) {
  __builtin_amdgcn_global_load_lds(
      (const __attribute__((address_space(1))) unsigned int*)g,
      (__attribute__((address_space(3))) unsigned int*)l, 16, 0, 0);
}

// Window-INTERLEAVED dataflow: fragments outer, windows inner. Each weight
// fragment (LDS qk / L1 vB,woutB) is loaded ONCE per wave and feeds two
// independent MFMA chains -> half the loads/waits, 2x ILP per load latency.
// launch_bounds(256,3): VGPR cap 170 >= peak demand (~130) -> no spill;
// LDS 36.9 KB caps residency at 3 blocks/CU regardless (measured r8/r10).
__global__ __launch_bounds__(256, 3)
void swin_fused(const float* __restrict__ x,
                const _Float16* __restrict__ wsh,
                const float* __restrict__ biasT,
                const float* __restrict__ b_out,
                float* __restrict__ out) {
  __shared__ _Float16 qkL[18432];   // 36864 B, frag-order
  const int tid  = threadIdx.x;
  const int wave = tid >> 6;
  const int lane = tid & 63;
  const int l15  = lane & 15;
  const int g    = lane >> 4;
  const int ty = l15 >> 2, tx = l15 & 3;

  const int blk   = blockIdx.x;
  const int batch = blk / 98;
  const int wbase = (blk % 98) * 8 + wave * 2;   // this wave's 2 windows

  // per-window token positions (cyclic shift folded in; reused for stores)
  int pp[2], qq[2];
#pragma unroll
  for (int w = 0; w < 2; ++w) {
    int wid = wbase + w;
    int wrow = wid / 28, wcol = wid % 28;
    int p = wrow * 4 + ty + 2; if (p >= 112) p -= 112;
    int q = wcol * 4 + tx + 2; if (q >= 112) q -= 112;
    pp[w] = p; qq[w] = q;
  }

  // ---- issue x loads
  float4_t xa[2][3], xb[2][3];
#pragma unroll
  for (int w = 0; w < 2; ++w) {
    const float* xr = x + (((size_t)batch * 112 + pp[w]) * 112 + qq[w]) * 96 + g * 8;
#pragma unroll
    for (int kt = 0; kt < 3; ++kt) {
      xa[w][kt] = *(const float4_t*)(xr + kt * 32);
      xb[w][kt] = *(const float4_t*)(xr + kt * 32 + 4);
    }
  }

  // ---- async stage qkF (linear copy: 2304 16B chunks over 4 waves x 9 iters)
  {
    const char* gs = (const char*)wsh;
    char* lb = (char*)qkL;
#pragma unroll
    for (int k = 0; k < 9; ++k) {
      int cb = k * 256 + wave * 64;          // wave-uniform chunk base
      size_t off = (size_t)(cb + lane) * 16;
      gload_lds16(gs + off, lb + off);
    }
  }

  // ---- per-window bias values
  float bb0[2], bb1[2], bb2[2], bb3[2];
#pragma unroll
  for (int w = 0; w < 2; ++w) {
    int wid = wbase + w;
    int var = ((wid / 28) == 27 ? 1 : 0) + ((wid % 28) == 27 ? 2 : 0);
    const float* bt = biasT + var * 256 + g * 64 + l15;   // [var][j=4g+r][i=l15]
    bb0[w] = bt[0]; bb1[w] = bt[16]; bb2[w] = bt[32]; bb3[w] = bt[48];
  }

  // ---- convert x to f16 fragments
  half8_t xf[2][3];
#pragma unroll
  for (int w = 0; w < 2; ++w)
#pragma unroll
    for (int kt = 0; kt < 3; ++kt) {
      half8_t h;
      h[0] = (_Float16)xa[w][kt][0]; h[1] = (_Float16)xa[w][kt][1];
      h[2] = (_Float16)xa[w][kt][2]; h[3] = (_Float16)xa[w][kt][3];
      h[4] = (_Float16)xb[w][kt][0]; h[5] = (_Float16)xb[w][kt][1];
      h[6] = (_Float16)xb[w][kt][2]; h[7] = (_Float16)xb[w][kt][3];
      xf[w][kt] = h;
    }

  __syncthreads();   // staging complete (barrier drains vmcnt incl. global_load_lds)

  const _Float16* vB    = wsh + VB_OFF;
  const _Float16* woutB = wsh + WOUTB_OFF;
  const float scale = 0.17677669529663687f;  // 32^-0.5

  // ---- GEMM1 qk tiles, interleaved: one frag load feeds BOTH windows
  half4_t qk16[2][12];
#pragma unroll
  for (int f = 0; f < 12; ++f) {
    half8_t w0 = *(const half8_t*)&qkL[((f * 3 + 0) * 64 + lane) * 8];
    half8_t w1 = *(const half8_t*)&qkL[((f * 3 + 1) * 64 + lane) * 8];
    half8_t w2 = *(const half8_t*)&qkL[((f * 3 + 2) * 64 + lane) * 8];
    float4_t a0 = {0.f, 0.f, 0.f, 0.f};
    float4_t a1 = {0.f, 0.f, 0.f, 0.f};
    a0 = __builtin_amdgcn_mfma_f32_16x16x32_f16(w0, xf[0][0], a0, 0, 0, 0);
    a1 = __builtin_amdgcn_mfma_f32_16x16x32_f16(w0, xf[1][0], a1, 0, 0, 0);
    a0 = __builtin_amdgcn_mfma_f32_16x16x32_f16(w1, xf[0][1], a0, 0, 0, 0);
    a1 = __builtin_amdgcn_mfma_f32_16x16x32_f16(w1, xf[1][1], a1, 0, 0, 0);
    a0 = __builtin_amdgcn_mfma_f32_16x16x32_f16(w2, xf[0][2], a0, 0, 0, 0);
    a1 = __builtin_amdgcn_mfma_f32_16x16x32_f16(w2, xf[1][2], a1, 0, 0, 0);
    qk16[0][f] = pack4(a0);
    qk16[1][f] = pack4(a1);
  }

  // ---- GEMM1 v tiles, interleaved
  half4_t vt16[2][6];
#pragma unroll
  for (int f6 = 0; f6 < 6; ++f6) {
    half8_t vb0 = *(const half8_t*)&vB[((f6 * 3 + 0) * 64 + lane) * 8];
    half8_t vb1 = *(const half8_t*)&vB[((f6 * 3 + 1) * 64 + lane) * 8];
    half8_t vb2 = *(const half8_t*)&vB[((f6 * 3 + 2) * 64 + lane) * 8];
    float4_t a0 = {0.f, 0.f, 0.f, 0.f};
    float4_t a1 = {0.f, 0.f, 0.f, 0.f};
    a0 = __builtin_amdgcn_mfma_f32_16x16x32_f16(xf[0][0], vb0, a0, 0, 0, 0);
    a1 = __builtin_amdgcn_mfma_f32_16x16x32_f16(xf[1][0], vb0, a1, 0, 0, 0);
    a0 = __builtin_amdgcn_mfma_f32_16x16x32_f16(xf[0][1], vb1, a0, 0, 0, 0);
    a1 = __builtin_amdgcn_mfma_f32_16x16x32_f16(xf[1][1], vb1, a1, 0, 0, 0);
    a0 = __builtin_amdgcn_mfma_f32_16x16x32_f16(xf[0][2], vb2, a0, 0, 0, 0);
    a1 = __builtin_amdgcn_mfma_f32_16x16x32_f16(xf[1][2], vb2, a1, 0, 0, 0);
    vt16[0][f6] = pack4(a0);
    vt16[1][f6] = pack4(a1);
  }

  // ---- attention, interleaved: QK^T + exp (no max-subtract), batched shuffles
  float ps[2][3][4], ss[2][3];
#pragma unroll
  for (int h = 0; h < 3; ++h)
#pragma unroll
    for (int w = 0; w < 2; ++w) {
      float4_t dd = {0.f, 0.f, 0.f, 0.f};
      dd = __builtin_amdgcn_mfma_f32_16x16x16f16(qk16[w][6 + 2 * h], qk16[w][2 * h],     dd, 0, 0, 0);
      dd = __builtin_amdgcn_mfma_f32_16x16x16f16(qk16[w][7 + 2 * h], qk16[w][2 * h + 1], dd, 0, 0, 0);
      ps[w][h][0] = __expf(fmaf(dd[0], scale, bb0[w]));
      ps[w][h][1] = __expf(fmaf(dd[1], scale, bb1[w]));
      ps[w][h][2] = __expf(fmaf(dd[2], scale, bb2[w]));
      ps[w][h][3] = __expf(fmaf(dd[3], scale, bb3[w]));
      ss[w][h] = (ps[w][h][0] + ps[w][h][1]) + (ps[w][h][2] + ps[w][h][3]);
    }
  // 12 independent cross-lane reduces, one latency exposure
#pragma unroll
  for (int w = 0; w < 2; ++w)
#pragma unroll
    for (int h = 0; h < 3; ++h)
      ss[w][h] += __shfl_xor(ss[w][h], 16, 64);
#pragma unroll
  for (int w = 0; w < 2; ++w)
#pragma unroll
    for (int h = 0; h < 3; ++h)
      ss[w][h] += __shfl_xor(ss[w][h], 32, 64);

  half4_t ao[2][6];
#pragma unroll
  for (int h = 0; h < 3; ++h)
#pragma unroll
    for (int w = 0; w < 2; ++w) {
      float r = __builtin_amdgcn_rcpf(ss[w][h]);
      half4_t pb;   // P^T: B operand (col=query l15, k=key 4g+r)
      pb[0] = (_Float16)(ps[w][h][0] * r); pb[1] = (_Float16)(ps[w][h][1] * r);
      pb[2] = (_Float16)(ps[w][h][2] * r); pb[3] = (_Float16)(ps[w][h][3] * r);
      float4_t o0 = {0.f, 0.f, 0.f, 0.f};
      o0 = __builtin_amdgcn_mfma_f32_16x16x16f16(vt16[w][2 * h], pb, o0, 0, 0, 0);
      ao[w][2 * h] = pack4(o0);
      float4_t o1 = {0.f, 0.f, 0.f, 0.f};
      o1 = __builtin_amdgcn_mfma_f32_16x16x16f16(vt16[w][2 * h + 1], pb, o1, 0, 0, 0);
      ao[w][2 * h + 1] = pack4(o1);
    }

  // ---- GEMM3 interleaved: one Wout frag load feeds both windows
  float* orow0 = out + (((size_t)batch * 112 + pp[0]) * 112 + qq[0]) * 96;
  float* orow1 = out + (((size_t)batch * 112 + pp[1]) * 112 + qq[1]) * 96;
#pragma unroll
  for (int mt = 0; mt < 6; ++mt) {
    float4_t a0 = {0.f, 0.f, 0.f, 0.f};
    float4_t a1 = {0.f, 0.f, 0.f, 0.f};
#pragma unroll
    for (int kp = 0; kp < 3; ++kp) {
      half8_t wp = *(const half8_t*)&woutB[((mt * 3 + kp) * 64 + lane) * 8];
      half4_t lo = __builtin_shufflevector(wp, wp, 0, 1, 2, 3);
      half4_t hi = __builtin_shufflevector(wp, wp, 4, 5, 6, 7);
      a0 = __builtin_amdgcn_mfma_f32_16x16x16f16(lo, ao[0][2 * kp],     a0, 0, 0, 0);
      a1 = __builtin_amdgcn_mfma_f32_16x16x16f16(lo, ao[1][2 * kp],     a1, 0, 0, 0);
      a0 = __builtin_amdgcn_mfma_f32_16x16x16f16(hi, ao[0][2 * kp + 1], a0, 0, 0, 0);
      a1 = __builtin_amdgcn_mfma_f32_16x16x16f16(hi, ao[1][2 * kp + 1], a1, 0, 0, 0);
    }
    float4_t bb = *(const float4_t*)&b_out[mt * 16 + g * 4];
    a0[0] += bb[0]; a0[1] += bb[1]; a0[2] += bb[2]; a0[3] += bb[3];
    a1[0] += bb[0]; a1[1] += bb[1]; a1[2] += bb[2]; a1[3] += bb[3];
    *(float4_t*)&orow0[mt * 16 + g * 4] = a0;
    *(float4_t*)&orow1[mt * 16 + g * 4] = a1;
  }
}

extern "C" void kernel_launch(void* const* d_in, const int* in_sizes, int n_in,
                              void* d_out, int out_size, void* d_ws, size_t ws_size,
                              hipStream_t stream) {
  const float* x    = (const float*)d_in[0];
  const float* Wqkv = (const float*)d_in[1];
  const float* pos  = (const float*)d_in[2];
  const float* Wout = (const float*)d_in[3];
  const float* bout = (const float*)d_in[4];
  char* ws = (char*)d_ws;
  _Float16* wsh  = (_Float16*)ws;
  float* biasT = (float*)(ws + BIAST_OFF_B);

  prep_kernel<<<148, 256, 0, stream>>>(Wqkv, Wout, pos, wsh, biasT);
  swin_fused<<<3136, 256, 0, stream>>>(x, wsh, biasT, bout, (float*)d_out);
}

// Round 12
// 92.744 us; speedup vs baseline: 1.3273x; 1.0376x over previous
//
#include <hip/hip_runtime.h>

typedef _Float16 half8_t __attribute__((ext_vector_type(8)));
typedef _Float16 half4_t __attribute__((ext_vector_type(4)));
typedef float    float4_t __attribute__((ext_vector_type(4)));

// ---------------- ws layout (f16 elements unless noted) ----------------
// [0, 18432)        qkF   frag-order q,k weights:
//                   qkF[((f*3+kt)*64+lane)*8+j] = W_qkv[(kt*32+(lane>>4)*8+j)*288 + f*16+(lane&15)], f in [0,12)
// [18432, 27648)    vB    frag-order v-weights:
//                   vB[((f6*3+kt)*64+lane)*8+j] = W_qkv[(kt*32+(lane>>4)*8+j)*288 + 192+f6*16+(lane&15)]
// [27648, 36864)    woutB frag-order Wout (kt-pairs):
//                   woutB[((mt*3+kp)*64+lane)*8+s] = W_out[((2*kp+(s>>2))*16+(lane>>4)*4+(s&3))*96 + mt*16+(lane&15)]
// [36864 f16 = 73728 B, 77824 B)  biasT f32 [4][16][16]: biasT[m][j][i] = bias_m[i][j]
#define VB_OFF 18432
#define WOUTB_OFF 27648
#define BIAST_OFF_B 73728

__global__ void prep_kernel(const float* __restrict__ Wqkv,
                            const float* __restrict__ Wout,
                            const float* __restrict__ pos,
                            _Float16* __restrict__ wsh,
                            float* __restrict__ biasT) {
  int idx = blockIdx.x * 256 + threadIdx.x;
  if (idx < 18432) {
    int j = idx & 7, lane = (idx >> 3) & 63, fk = idx >> 9;   // fk in [0,36)
    int f = fk / 3, kt = fk % 3;
    int l15 = lane & 15, g = lane >> 4;
    int k = kt * 32 + g * 8 + j;                // input feature
    int fo = f * 16 + l15;                      // q,k output feature row
    wsh[idx] = (_Float16)Wqkv[k * 288 + fo];
  } else if (idx < 27648) {
    int t = idx - VB_OFF;
    int j = t & 7, lane = (t >> 3) & 63, fk = t >> 9;         // fk in [0,18)
    int f6 = fk / 3, kt = fk % 3;
    int l15 = lane & 15, g = lane >> 4;
    int k = kt * 32 + g * 8 + j;
    int fo = 192 + f6 * 16 + l15;               // v output feature row
    wsh[idx] = (_Float16)Wqkv[k * 288 + fo];
  } else if (idx < 36864) {
    int t = idx - WOUTB_OFF;
    int s = t & 7, lane = (t >> 3) & 63, fk = t >> 9;         // fk in [0,18)
    int mt = fk / 3, kp = fk % 3;
    int l15 = lane & 15, g = lane >> 4;
    int kt = kp * 2 + (s >> 2), j = s & 3;
    int k = kt * 16 + g * 4 + j;                // attn feature
    int fo = mt * 16 + l15;                     // out feature
    wsh[idx] = (_Float16)Wout[k * 96 + fo];
  } else if (idx < 36864 + 1024) {
    int t = idx - 36864;
    int m = t >> 8, j = (t >> 4) & 15, i = t & 15;            // store [j][i] = bias[i][j]
    int xi = i >> 2, yi = i & 3, xj = j >> 2, yj = j & 3;
    float v = pos[(xj - xi + 3) * 7 + (yj - yi + 3)];         // key minus query
    if ((m & 1) && ((i >= 8) != (j >= 8))) v -= 1e9f;         // ul mask (last window row)
    if ((m & 2) && ((yi >= 2) != (yj >= 2))) v -= 1e9f;       // lr mask (last window col)
    biasT[t] = v;
  }
}

static __device__ __forceinline__ half4_t pack4(float4_t a) {
  half4_t h;
  h[0] = (_Float16)a[0]; h[1] = (_Float16)a[1];
  h[2] = (_Float16)a[2]; h[3] = (_Float16)a[3];
  return h;
}

static __device__ __forceinline__ void gload_lds16(const void* g, void* l) {
  __builtin_amdgcn_global_load_lds(
      (const __attribute__((address_space(1))) unsigned int*)g,
      (__attribute__((address_space(3))) unsigned int*)l, 16, 0, 0);
}

// 512-thread blocks (8 waves), 2 windows/wave, 16 windows/block. ALL weight
// fragments (qk + v + wout, 73728 B = 9x8KB exact) staged in LDS -> zero
// L1/L2 latency in the compute loop; 2 blocks/CU = 16 waves/CU provided
// VGPR <= 128 -> launch_bounds(512,4) (r11 structure compiled at 68 VGPR).
// Window-interleaved dataflow: each frag load feeds both windows' MFMA chains.
__global__ __launch_bounds__(512, 4)
void swin_fused(const float* __restrict__ x,
                const _Float16* __restrict__ wsh,
                const float* __restrict__ biasT,
                const float* __restrict__ b_out,
                float* __restrict__ out) {
  __shared__ _Float16 wL[36864];   // 73728 B: qkF | vB | woutB, frag-order
  const int tid  = threadIdx.x;
  const int wave = tid >> 6;
  const int lane = tid & 63;
  const int l15  = lane & 15;
  const int g    = lane >> 4;
  const int ty = l15 >> 2, tx = l15 & 3;

  const int blk   = blockIdx.x;
  const int batch = blk / 49;
  const int wbase = (blk % 49) * 16 + wave * 2;   // this wave's 2 windows

  // per-window token positions (cyclic shift folded in; reused for stores)
  int pp[2], qq[2];
#pragma unroll
  for (int w = 0; w < 2; ++w) {
    int wid = wbase + w;
    int wrow = wid / 28, wcol = wid % 28;
    int p = wrow * 4 + ty + 2; if (p >= 112) p -= 112;
    int q = wcol * 4 + tx + 2; if (q >= 112) q -= 112;
    pp[w] = p; qq[w] = q;
  }

  // ---- issue x loads
  float4_t xa[2][3], xb[2][3];
#pragma unroll
  for (int w = 0; w < 2; ++w) {
    const float* xr = x + (((size_t)batch * 112 + pp[w]) * 112 + qq[w]) * 96 + g * 8;
#pragma unroll
    for (int kt = 0; kt < 3; ++kt) {
      xa[w][kt] = *(const float4_t*)(xr + kt * 32);
      xb[w][kt] = *(const float4_t*)(xr + kt * 32 + 4);
    }
  }

  // ---- async stage ALL weight frags (4608 16B chunks = 9 iters x 512 thr)
  {
    const char* gs = (const char*)wsh;
    char* lb = (char*)wL;
#pragma unroll
    for (int k = 0; k < 9; ++k) {
      int cb = k * 512 + wave * 64;          // wave-uniform chunk base
      size_t off = (size_t)(cb + lane) * 16;
      gload_lds16(gs + off, lb + off);
    }
  }

  // ---- per-window bias values
  float bb0[2], bb1[2], bb2[2], bb3[2];
#pragma unroll
  for (int w = 0; w < 2; ++w) {
    int wid = wbase + w;
    int var = ((wid / 28) == 27 ? 1 : 0) + ((wid % 28) == 27 ? 2 : 0);
    const float* bt = biasT + var * 256 + g * 64 + l15;   // [var][j=4g+r][i=l15]
    bb0[w] = bt[0]; bb1[w] = bt[16]; bb2[w] = bt[32]; bb3[w] = bt[48];
  }

  // ---- convert x to f16 fragments
  half8_t xf[2][3];
#pragma unroll
  for (int w = 0; w < 2; ++w)
#pragma unroll
    for (int kt = 0; kt < 3; ++kt) {
      half8_t h;
      h[0] = (_Float16)xa[w][kt][0]; h[1] = (_Float16)xa[w][kt][1];
      h[2] = (_Float16)xa[w][kt][2]; h[3] = (_Float16)xa[w][kt][3];
      h[4] = (_Float16)xb[w][kt][0]; h[5] = (_Float16)xb[w][kt][1];
      h[6] = (_Float16)xb[w][kt][2]; h[7] = (_Float16)xb[w][kt][3];
      xf[w][kt] = h;
    }

  __syncthreads();   // staging complete (barrier drains vmcnt incl. global_load_lds)

  const _Float16* qkF = wL;
  const _Float16* vF  = wL + VB_OFF;
  const _Float16* woF = wL + WOUTB_OFF;
  const float scale = 0.17677669529663687f;  // 32^-0.5

  // ---- GEMM1 qk tiles, interleaved: one frag load feeds BOTH windows
  half4_t qk16[2][12];
#pragma unroll
  for (int f = 0; f < 12; ++f) {
    half8_t w0 = *(const half8_t*)&qkF[((f * 3 + 0) * 64 + lane) * 8];
    half8_t w1 = *(const half8_t*)&qkF[((f * 3 + 1) * 64 + lane) * 8];
    half8_t w2 = *(const half8_t*)&qkF[((f * 3 + 2) * 64 + lane) * 8];
    float4_t a0 = {0.f, 0.f, 0.f, 0.f};
    float4_t a1 = {0.f, 0.f, 0.f, 0.f};
    a0 = __builtin_amdgcn_mfma_f32_16x16x32_f16(w0, xf[0][0], a0, 0, 0, 0);
    a1 = __builtin_amdgcn_mfma_f32_16x16x32_f16(w0, xf[1][0], a1, 0, 0, 0);
    a0 = __builtin_amdgcn_mfma_f32_16x16x32_f16(w1, xf[0][1], a0, 0, 0, 0);
    a1 = __builtin_amdgcn_mfma_f32_16x16x32_f16(w1, xf[1][1], a1, 0, 0, 0);
    a0 = __builtin_amdgcn_mfma_f32_16x16x32_f16(w2, xf[0][2], a0, 0, 0, 0);
    a1 = __builtin_amdgcn_mfma_f32_16x16x32_f16(w2, xf[1][2], a1, 0, 0, 0);
    qk16[0][f] = pack4(a0);
    qk16[1][f] = pack4(a1);
  }

  // ---- GEMM1 v tiles, interleaved
  half4_t vt16[2][6];
#pragma unroll
  for (int f6 = 0; f6 < 6; ++f6) {
    half8_t vb0 = *(const half8_t*)&vF[((f6 * 3 + 0) * 64 + lane) * 8];
    half8_t vb1 = *(const half8_t*)&vF[((f6 * 3 + 1) * 64 + lane) * 8];
    half8_t vb2 = *(const half8_t*)&vF[((f6 * 3 + 2) * 64 + lane) * 8];
    float4_t a0 = {0.f, 0.f, 0.f, 0.f};
    float4_t a1 = {0.f, 0.f, 0.f, 0.f};
    a0 = __builtin_amdgcn_mfma_f32_16x16x32_f16(xf[0][0], vb0, a0, 0, 0, 0);
    a1 = __builtin_amdgcn_mfma_f32_16x16x32_f16(xf[1][0], vb0, a1, 0, 0, 0);
    a0 = __builtin_amdgcn_mfma_f32_16x16x32_f16(xf[0][1], vb1, a0, 0, 0, 0);
    a1 = __builtin_amdgcn_mfma_f32_16x16x32_f16(xf[1][1], vb1, a1, 0, 0, 0);
    a0 = __builtin_amdgcn_mfma_f32_16x16x32_f16(xf[0][2], vb2, a0, 0, 0, 0);
    a1 = __builtin_amdgcn_mfma_f32_16x16x32_f16(xf[1][2], vb2, a1, 0, 0, 0);
    vt16[0][f6] = pack4(a0);
    vt16[1][f6] = pack4(a1);
  }

  // ---- attention, interleaved: QK^T + exp (no max-subtract), batched shuffles
  float ps[2][3][4], ss[2][3];
#pragma unroll
  for (int h = 0; h < 3; ++h)
#pragma unroll
    for (int w = 0; w < 2; ++w) {
      float4_t dd = {0.f, 0.f, 0.f, 0.f};
      dd = __builtin_amdgcn_mfma_f32_16x16x16f16(qk16[w][6 + 2 * h], qk16[w][2 * h],     dd, 0, 0, 0);
      dd = __builtin_amdgcn_mfma_f32_16x16x16f16(qk16[w][7 + 2 * h], qk16[w][2 * h + 1], dd, 0, 0, 0);
      ps[w][h][0] = __expf(fmaf(dd[0], scale, bb0[w]));
      ps[w][h][1] = __expf(fmaf(dd[1], scale, bb1[w]));
      ps[w][h][2] = __expf(fmaf(dd[2], scale, bb2[w]));
      ps[w][h][3] = __expf(fmaf(dd[3], scale, bb3[w]));
      ss[w][h] = (ps[w][h][0] + ps[w][h][1]) + (ps[w][h][2] + ps[w][h][3]);
    }
  // 12 independent cross-lane reduces, one latency exposure
#pragma unroll
  for (int w = 0; w < 2; ++w)
#pragma unroll
    for (int h = 0; h < 3; ++h)
      ss[w][h] += __shfl_xor(ss[w][h], 16, 64);
#pragma unroll
  for (int w = 0; w < 2; ++w)
#pragma unroll
    for (int h = 0; h < 3; ++h)
      ss[w][h] += __shfl_xor(ss[w][h], 32, 64);

  half4_t ao[2][6];
#pragma unroll
  for (int h = 0; h < 3; ++h)
#pragma unroll
    for (int w = 0; w < 2; ++w) {
      float r = __builtin_amdgcn_rcpf(ss[w][h]);
      half4_t pb;   // P^T: B operand (col=query l15, k=key 4g+r)
      pb[0] = (_Float16)(ps[w][h][0] * r); pb[1] = (_Float16)(ps[w][h][1] * r);
      pb[2] = (_Float16)(ps[w][h][2] * r); pb[3] = (_Float16)(ps[w][h][3] * r);
      float4_t o0 = {0.f, 0.f, 0.f, 0.f};
      o0 = __builtin_amdgcn_mfma_f32_16x16x16f16(vt16[w][2 * h], pb, o0, 0, 0, 0);
      ao[w][2 * h] = pack4(o0);
      float4_t o1 = {0.f, 0.f, 0.f, 0.f};
      o1 = __builtin_amdgcn_mfma_f32_16x16x16f16(vt16[w][2 * h + 1], pb, o1, 0, 0, 0);
      ao[w][2 * h + 1] = pack4(o1);
    }

  // ---- GEMM3 interleaved; preload ALL 18 Wout frag-pairs (regs free here)
  half8_t wo[18];
#pragma unroll
  for (int i = 0; i < 18; ++i)
    wo[i] = *(const half8_t*)&woF[(i * 64 + lane) * 8];

  float* orow0 = out + (((size_t)batch * 112 + pp[0]) * 112 + qq[0]) * 96;
  float* orow1 = out + (((size_t)batch * 112 + pp[1]) * 112 + qq[1]) * 96;
#pragma unroll
  for (int mt = 0; mt < 6; ++mt) {
    float4_t a0 = {0.f, 0.f, 0.f, 0.f};
    float4_t a1 = {0.f, 0.f, 0.f, 0.f};
#pragma unroll
    for (int kp = 0; kp < 3; ++kp) {
      half8_t wp = wo[mt * 3 + kp];
      half4_t lo = __builtin_shufflevector(wp, wp, 0, 1, 2, 3);
      half4_t hi = __builtin_shufflevector(wp, wp, 4, 5, 6, 7);
      a0 = __builtin_amdgcn_mfma_f32_16x16x16f16(lo, ao[0][2 * kp],     a0, 0, 0, 0);
      a1 = __builtin_amdgcn_mfma_f32_16x16x16f16(lo, ao[1][2 * kp],     a1, 0, 0, 0);
      a0 = __builtin_amdgcn_mfma_f32_16x16x16f16(hi, ao[0][2 * kp + 1], a0, 0, 0, 0);
      a1 = __builtin_amdgcn_mfma_f32_16x16x16f16(hi, ao[1][2 * kp + 1], a1, 0, 0, 0);
    }
    float4_t bb = *(const float4_t*)&b_out[mt * 16 + g * 4];
    a0[0] += bb[0]; a0[1] += bb[1]; a0[2] += bb[2]; a0[3] += bb[3];
    a1[0] += bb[0]; a1[1] += bb[1]; a1[2] += bb[2]; a1[3] += bb[3];
    *(float4_t*)&orow0[mt * 16 + g * 4] = a0;
    *(float4_t*)&orow1[mt * 16 + g * 4] = a1;
  }
}

extern "C" void kernel_launch(void* const* d_in, const int* in_sizes, int n_in,
                              void* d_out, int out_size, void* d_ws, size_t ws_size,
                              hipStream_t stream) {
  const float* x    = (const float*)d_in[0];
  const float* Wqkv = (const float*)d_in[1];
  const float* pos  = (const float*)d_in[2];
  const float* Wout = (const float*)d_in[3];
  const float* bout = (const float*)d_in[4];
  char* ws = (char*)d_ws;
  _Float16* wsh  = (_Float16*)ws;
  float* biasT = (float*)(ws + BIAST_OFF_B);

  prep_kernel<<<148, 256, 0, stream>>>(Wqkv, Wout, pos, wsh, biasT);
  swin_fused<<<1568, 512, 0, stream>>>(x, wsh, biasT, bout, (float*)d_out);
}